// Round 1
// baseline (209.550 us; speedup 1.0000x reference)
//
#include <hip/hip_runtime.h>
#include <hip/hip_bf16.h>
#include <cstdint>
#include <cstddef>

typedef short short8 __attribute__((ext_vector_type(8)));
typedef float f32x4 __attribute__((ext_vector_type(4)));

#define NS    2048
#define KPAD  288     // 285 sig channels padded to 288
#define H2    512
#define HID   256
#define WPB   56      // windows per sig workgroup (8 waves x 7)
#define SBLK  37      // ceil(2048/56)

// ---- compile-time necklace-representative table: (i,j,k) -> feat col (45+rank) or -1
struct Tbl3 { short col[729]; };
static constexpr Tbl3 make_tbl3() {
    Tbl3 t{};
    for (int x = 0; x < 729; ++x) t.col[x] = -1;
    int r = 0;
    for (int i = 0; i < 9; ++i)
        for (int j = 0; j < 9; ++j)
            for (int k = 0; k < 9; ++k) {
                // (i,j,k) < (j,k,i)  and  (i,j,k) < (k,i,j)   (lexicographic, strict)
                bool lt1 = (i < j) || (i == j && (j < k || (j == k && k < i)));
                bool lt2 = (i < k) || (i == k && (j < i || (j == i && k < j)));
                if (lt1 && lt2) { t.col[(i*9+j)*9+k] = (short)(45 + r); ++r; }
            }
    return t;
}
static constexpr Tbl3 TBL3 = make_tbl3();

// ============================================================================
// Signature kernel: one lane per (window, slab i).  Lane keeps S3[i][.][.]
// (81 regs), S2 row i (9), S1_i.  56 windows / workgroup of 512 threads.
// ============================================================================
__global__ __launch_bounds__(512, 2) void sig_kernel(const float* __restrict__ x,
                                                     __hip_bfloat16* __restrict__ feats) {
    __shared__ __align__(16) float X[115 * 8];
    __shared__ float S2buf[WPB * 81];
    __shared__ float S1buf[WPB * 9];

    const int blk = blockIdx.x;
    const int b   = blk / SBLK;
    const int s0  = (blk % SBLK) * WPB;
    const int lo  = (s0 - 59 > 0) ? (s0 - 59) : 0;
    const int hi  = (s0 + WPB - 1 < NS - 1) ? (s0 + WPB - 1) : (NS - 1);
    const int nrow = hi - lo + 1;     // <= 115
    const int tid = threadIdx.x;

    {   // stage x[b, lo..hi, 0..7] -> LDS (row-major [pos][ch])
        const float4* src = (const float4*)(x + ((size_t)b * NS + lo) * 8);
        float4* dst = (float4*)X;
        const int n4 = nrow * 2;
        for (int t = tid; t < n4; t += 512) dst[t] = src[t];
    }
    __syncthreads();

    const int lane = tid & 63;
    const int wave = tid >> 6;
    const int wl   = lane / 9;            // 0..7 (7 == idle duplicate lane)
    const int ci   = lane - wl * 9;       // slab index i in 0..8
    const int wl6  = (wl < 6) ? wl : 6;
    const int widx = wave * 7 + wl6;      // 0..55
    const int s    = s0 + widx;
    const bool act = (wl < 7) && (s < NS);

    float S3[9][9];
    float S2r[9];
    float S1i = 0.0f;
#pragma unroll
    for (int a = 0; a < 9; ++a) {
        S2r[a] = 0.0f;
#pragma unroll
        for (int c = 0; c < 9; ++c) S3[a][c] = 0.0f;
    }
    float prev[8];
#pragma unroll
    for (int c = 0; c < 8; ++c) prev[c] = 0.0f;
    float pscal = 0.0f;
    const int ioff = (ci > 0) ? (ci - 1) : 0;
    const int sm59 = s - 59;
    const float DT = 1.0f / 59.0f;

#pragma unroll 2
    for (int j = 0; j < 60; ++j) {
        int g = sm59 + j; g = (g > 0) ? g : 0;          // left-clamped window index
        const float* row = &X[(g - lo) * 8];
        const float4 c0 = *(const float4*)(row);
        const float4 c1 = *(const float4*)(row + 4);
        const float rs  = row[ioff];                    // scalar for this lane's slab
        const float dtj = (j == 0) ? 0.0f : DT;         // time-channel increment
        float v[9];
        v[0] = dtj;
        v[1] = c0.x - prev[0]; v[2] = c0.y - prev[1];
        v[3] = c0.z - prev[2]; v[4] = c0.w - prev[3];
        v[5] = c1.x - prev[4]; v[6] = c1.y - prev[5];
        v[7] = c1.z - prev[6]; v[8] = c1.w - prev[7];
        const float vi = (ci == 0) ? dtj : (rs - pscal);
        // S3 update first (old S1, S2):  S3[j][k] += (S2r[j] + (S1i/2 + vi/6)*v[j]) * v[k]
        const float hh = 0.5f * S1i + vi * (1.0f / 6.0f);
        float r[9];
#pragma unroll
        for (int a = 0; a < 9; ++a) r[a] = S2r[a] + hh * v[a];
#pragma unroll
        for (int a = 0; a < 9; ++a)
#pragma unroll
            for (int c = 0; c < 9; ++c) S3[a][c] += r[a] * v[c];
        // S2 update (old S1):  S2r[j] += (S1i + vi/2) * v[j]
        const float aa = S1i + 0.5f * vi;
#pragma unroll
        for (int a = 0; a < 9; ++a) S2r[a] += aa * v[a];
        S1i += vi;
        prev[0] = c0.x; prev[1] = c0.y; prev[2] = c0.z; prev[3] = c0.w;
        prev[4] = c1.x; prev[5] = c1.y; prev[6] = c1.z; prev[7] = c1.w;
        pscal = rs;
    }

    // cross-slab exchange (once): full S1 and S2 of each window into LDS
    if (wl < 7) {
        S1buf[widx * 9 + ci] = S1i;
#pragma unroll
        for (int a = 0; a < 9; ++a) S2buf[widx * 81 + ci * 9 + a] = S2r[a];
    }
    __syncthreads();

    float s1v[9];
#pragma unroll
    for (int a = 0; a < 9; ++a) s1v[a] = S1buf[widx * 9 + a];
    const float* S2w = &S2buf[widx * 81];

    __hip_bfloat16* frow = feats + (size_t)(b * NS + (act ? s : 0)) * KPAD;
    if (act) {
        // L1 = S1
        frow[ci] = __float2bfloat16(S1i);
        // L2[i,j] = S2[i,j] - 0.5 S1_i S1_j   (i<j), col = 9 + rank
#pragma unroll
        for (int j2 = 0; j2 < 9; ++j2) {
            if (ci < j2) {
                const float val = S2r[j2] - 0.5f * S1i * s1v[j2];
                const int col = 9 + ci * 8 - (ci * (ci - 1)) / 2 + (j2 - ci - 1);
                frow[col] = __float2bfloat16(val);
            }
        }
        if (ci == 0) {  // zero the K padding
            frow[285] = __float2bfloat16(0.0f);
            frow[286] = __float2bfloat16(0.0f);
            frow[287] = __float2bfloat16(0.0f);
        }
    }
    // L3[i,j,k] = S3 - 0.5(S1_i S2[j,k] + S2[i,j] S1_k) + S1_i S1_j S1_k / 3
#pragma unroll
    for (int jk = 0; jk < 81; ++jk) {
        const int j3 = jk / 9, k3 = jk % 9;
        const int col = TBL3.col[ci * 81 + jk];
        if (act && col >= 0) {
            const float s2jk = S2w[jk];
            const float val = S3[j3][k3]
                - 0.5f * (S1i * s2jk + S2r[j3] * s1v[k3])
                + S1i * s1v[j3] * s1v[k3] * (1.0f / 3.0f);
            frow[col] = __float2bfloat16(val);
        }
    }
}

// ============================================================================
// Weight transpose/cast kernels (tiny): w1[285][512]f32 -> w1T[512][288]bf16,
// w2[512][256]f32 -> w2T[256][512]bf16.  [n][k] layout => B-frag ds_read_b128.
// ============================================================================
__global__ void convert_w1(const float* __restrict__ w1, __hip_bfloat16* __restrict__ w1T) {
    const int n = blockIdx.x;          // 0..511
    const int k = threadIdx.x;         // 0..287
    const float v = (k < 285) ? w1[(size_t)k * H2 + n] : 0.0f;
    w1T[(size_t)n * KPAD + k] = __float2bfloat16(v);
}
__global__ void convert_w2(const float* __restrict__ w2, __hip_bfloat16* __restrict__ w2T) {
    const int n = blockIdx.x;          // 0..255
    const int k = threadIdx.x;         // 0..511
    w2T[(size_t)n * H2 + k] = __float2bfloat16(w2[(size_t)k * HID + n]);
}

// ============================================================================
// GEMM1: h = LN(GELU(feats @ w1 + b1)) -> bf16.  Block = 64 rows x 512 cols
// (full N so LN is fusable).  8 waves, wave tile 64x64, 16x16x32 bf16 MFMA.
// ============================================================================
__global__ __launch_bounds__(512, 2) void gemm1_kernel(
        const __hip_bfloat16* __restrict__ feats,
        const __hip_bfloat16* __restrict__ w1T,
        const float* __restrict__ b1,
        const float* __restrict__ lng,
        const float* __restrict__ lnb,
        __hip_bfloat16* __restrict__ hbuf) {
    __shared__ __align__(16) __hip_bfloat16 ldsA[64 * 32];
    __shared__ __align__(16) __hip_bfloat16 ldsB[512 * 32];
    __shared__ float lnpart[8][64][2];
    __shared__ float lnstat[64][2];

    const int tid  = threadIdx.x;
    const int wave = tid >> 6;
    const int lane = tid & 63;
    const int quad = lane >> 4;
    const int l16  = lane & 15;
    const int m0   = blockIdx.x * 64;

    f32x4 acc[4][4];
#pragma unroll
    for (int mf = 0; mf < 4; ++mf)
#pragma unroll
        for (int nf = 0; nf < 4; ++nf) acc[mf][nf] = (f32x4){0.f, 0.f, 0.f, 0.f};

    for (int kt = 0; kt < 9; ++kt) {
        const int K0 = kt * 32;
        if (tid < 256) {               // A tile 64x32 (wave-uniform branch)
            const int m = tid >> 2, kc = tid & 3;
            ((uint4*)ldsA)[tid] = *(const uint4*)(feats + (size_t)(m0 + m) * KPAD + K0 + kc * 8);
        }
#pragma unroll
        for (int q = 0; q < 4; ++q) {  // B tile 512x32 ([n][k])
            const int chunk = q * 512 + tid;
            const int n = chunk >> 2, kc = chunk & 3;
            ((uint4*)ldsB)[chunk] = *(const uint4*)(w1T + (size_t)n * KPAD + K0 + kc * 8);
        }
        __syncthreads();
        short8 bfrag[4];
#pragma unroll
        for (int nf = 0; nf < 4; ++nf) {
            const int n = wave * 64 + nf * 16 + l16;
            bfrag[nf] = *(const short8*)(ldsB + n * 32 + quad * 8);
        }
#pragma unroll
        for (int mf = 0; mf < 4; ++mf) {
            const short8 afrag = *(const short8*)(ldsA + (mf * 16 + l16) * 32 + quad * 8);
#pragma unroll
            for (int nf = 0; nf < 4; ++nf)
                acc[mf][nf] = __builtin_amdgcn_mfma_f32_16x16x32_bf16(afrag, bfrag[nf], acc[mf][nf], 0, 0, 0);
        }
        __syncthreads();
    }

    // ---- epilogue: bias + exact GELU (C frag: row = quad*4+reg, col = l16) ----
    float bias[4];
#pragma unroll
    for (int nf = 0; nf < 4; ++nf) bias[nf] = b1[wave * 64 + nf * 16 + l16];
    float e[4][4][4];
#pragma unroll
    for (int mf = 0; mf < 4; ++mf)
#pragma unroll
        for (int nf = 0; nf < 4; ++nf)
#pragma unroll
            for (int r = 0; r < 4; ++r) {
                const float xv = acc[mf][nf][r] + bias[nf];
                e[mf][nf][r] = 0.5f * xv * (1.0f + erff(xv * 0.70710678118654752f));
            }
    // LayerNorm: per-row sum/sumsq; reduce over 16 lanes (cols) then 8 waves
    float psum[4][4], psq[4][4];
#pragma unroll
    for (int mf = 0; mf < 4; ++mf)
#pragma unroll
        for (int r = 0; r < 4; ++r) {
            float su = 0.f, sq = 0.f;
#pragma unroll
            for (int nf = 0; nf < 4; ++nf) { const float t = e[mf][nf][r]; su += t; sq += t * t; }
            psum[mf][r] = su; psq[mf][r] = sq;
        }
#pragma unroll
    for (int d = 1; d < 16; d <<= 1) {
#pragma unroll
        for (int mf = 0; mf < 4; ++mf)
#pragma unroll
            for (int r = 0; r < 4; ++r) {
                psum[mf][r] += __shfl_xor(psum[mf][r], d);
                psq[mf][r]  += __shfl_xor(psq[mf][r], d);
            }
    }
    if (l16 == 0) {
#pragma unroll
        for (int mf = 0; mf < 4; ++mf)
#pragma unroll
            for (int r = 0; r < 4; ++r) {
                const int rrow = mf * 16 + quad * 4 + r;
                lnpart[wave][rrow][0] = psum[mf][r];
                lnpart[wave][rrow][1] = psq[mf][r];
            }
    }
    __syncthreads();
    if (tid < 64) {
        float su = 0.f, sq = 0.f;
#pragma unroll
        for (int w = 0; w < 8; ++w) { su += lnpart[w][tid][0]; sq += lnpart[w][tid][1]; }
        const float mu  = su * (1.0f / 512.0f);
        const float var = sq * (1.0f / 512.0f) - mu * mu;   // population var (ddof=0)
        lnstat[tid][0] = mu;
        lnstat[tid][1] = rsqrtf(var + 1e-5f);
    }
    __syncthreads();
    float gv[4], bv[4];
#pragma unroll
    for (int nf = 0; nf < 4; ++nf) {
        const int col = wave * 64 + nf * 16 + l16;
        gv[nf] = lng[col]; bv[nf] = lnb[col];
    }
#pragma unroll
    for (int mf = 0; mf < 4; ++mf)
#pragma unroll
        for (int r = 0; r < 4; ++r) {
            const int rrow = mf * 16 + quad * 4 + r;
            const float mu = lnstat[rrow][0];
            const float rstd = lnstat[rrow][1];
#pragma unroll
            for (int nf = 0; nf < 4; ++nf) {
                const float hn = (e[mf][nf][r] - mu) * rstd * gv[nf] + bv[nf];
                hbuf[(size_t)(m0 + rrow) * H2 + wave * 64 + nf * 16 + l16] = __float2bfloat16(hn);
            }
        }
}

// ============================================================================
// GEMM2: out = h @ w2 + b2 (fp32 out). Block = 64 rows x 256 cols, 8 waves,
// wave tile 64x32, K=512 in 16 steps of 32.
// ============================================================================
__global__ __launch_bounds__(512, 2) void gemm2_kernel(
        const __hip_bfloat16* __restrict__ hbuf,
        const __hip_bfloat16* __restrict__ w2T,
        const float* __restrict__ b2,
        float* __restrict__ out) {
    __shared__ __align__(16) __hip_bfloat16 ldsA[64 * 32];
    __shared__ __align__(16) __hip_bfloat16 ldsB[256 * 32];
    const int tid  = threadIdx.x;
    const int wave = tid >> 6;
    const int lane = tid & 63;
    const int quad = lane >> 4;
    const int l16  = lane & 15;
    const int m0   = blockIdx.x * 64;

    f32x4 acc[4][2];
#pragma unroll
    for (int mf = 0; mf < 4; ++mf)
#pragma unroll
        for (int nf = 0; nf < 2; ++nf) acc[mf][nf] = (f32x4){0.f, 0.f, 0.f, 0.f};

    for (int kt = 0; kt < 16; ++kt) {
        const int K0 = kt * 32;
        if (tid < 256) {
            const int m = tid >> 2, kc = tid & 3;
            ((uint4*)ldsA)[tid] = *(const uint4*)(hbuf + (size_t)(m0 + m) * H2 + K0 + kc * 8);
        }
#pragma unroll
        for (int q = 0; q < 2; ++q) {
            const int chunk = q * 512 + tid;
            const int n = chunk >> 2, kc = chunk & 3;
            ((uint4*)ldsB)[chunk] = *(const uint4*)(w2T + (size_t)n * H2 + K0 + kc * 8);
        }
        __syncthreads();
        short8 bfrag[2];
#pragma unroll
        for (int nf = 0; nf < 2; ++nf) {
            const int n = wave * 32 + nf * 16 + l16;
            bfrag[nf] = *(const short8*)(ldsB + n * 32 + quad * 8);
        }
#pragma unroll
        for (int mf = 0; mf < 4; ++mf) {
            const short8 afrag = *(const short8*)(ldsA + (mf * 16 + l16) * 32 + quad * 8);
#pragma unroll
            for (int nf = 0; nf < 2; ++nf)
                acc[mf][nf] = __builtin_amdgcn_mfma_f32_16x16x32_bf16(afrag, bfrag[nf], acc[mf][nf], 0, 0, 0);
        }
        __syncthreads();
    }
    float bb[2];
#pragma unroll
    for (int nf = 0; nf < 2; ++nf) bb[nf] = b2[wave * 32 + nf * 16 + l16];
#pragma unroll
    for (int mf = 0; mf < 4; ++mf)
#pragma unroll
        for (int r = 0; r < 4; ++r) {
            const int rrow = mf * 16 + quad * 4 + r;
#pragma unroll
            for (int nf = 0; nf < 2; ++nf)
                out[(size_t)(m0 + rrow) * HID + wave * 32 + nf * 16 + l16] = acc[mf][nf][r] + bb[nf];
        }
}

// ============================================================================
extern "C" void kernel_launch(void* const* d_in, const int* in_sizes, int n_in,
                              void* d_out, int out_size, void* d_ws, size_t ws_size,
                              hipStream_t stream) {
    const float* x   = (const float*)d_in[0];
    const float* w1  = (const float*)d_in[1];
    const float* b1  = (const float*)d_in[2];
    const float* lng = (const float*)d_in[3];
    const float* lnb = (const float*)d_in[4];
    const float* w2  = (const float*)d_in[5];
    const float* b2  = (const float*)d_in[6];
    float* out = (float*)d_out;

    char* ws = (char*)d_ws;
    __hip_bfloat16* feats = (__hip_bfloat16*)(ws);                       // 16384*288*2 = 9437184
    __hip_bfloat16* hbuf  = (__hip_bfloat16*)(ws + 9437184);             // 16384*512*2 = 16777216
    __hip_bfloat16* w1T   = (__hip_bfloat16*)(ws + 9437184 + 16777216);  // 512*288*2  = 294912
    __hip_bfloat16* w2T   = (__hip_bfloat16*)(ws + 9437184 + 16777216 + 294912); // 256*512*2

    convert_w1<<<dim3(512), dim3(288), 0, stream>>>(w1, w1T);
    convert_w2<<<dim3(256), dim3(512), 0, stream>>>(w2, w2T);
    sig_kernel<<<dim3(8 * SBLK), dim3(512), 0, stream>>>(x, feats);
    gemm1_kernel<<<dim3(16384 / 64), dim3(512), 0, stream>>>(feats, w1T, b1, lng, lnb, hbuf);
    gemm2_kernel<<<dim3(16384 / 64), dim3(512), 0, stream>>>(hbuf, w2T, b2, out);
}

// Round 2
// 176.286 us; speedup vs baseline: 1.1887x; 1.1887x over previous
//
#include <hip/hip_runtime.h>
#include <hip/hip_bf16.h>
#include <cstdint>
#include <cstddef>

typedef short short8 __attribute__((ext_vector_type(8)));
typedef float f32x4 __attribute__((ext_vector_type(4)));

#define NS    2048
#define KPAD  288     // 285 sig channels padded to 288
#define H2    512
#define HID   256
#define WPB   14      // windows per sig workgroup (2 waves x 7)
#define SBLK  147     // ceil(2048/14)

// async global->LDS 16B: dst must be the WAVE-UNIFORM base; lane i lands at dst + i*16
__device__ __forceinline__ void gl2lds16(const void* g, void* l) {
    __builtin_amdgcn_global_load_lds(
        (const __attribute__((address_space(1))) void*)g,
        (__attribute__((address_space(3))) void*)l, 16, 0, 0);
}

// ---- compile-time necklace-representative table: (i,j,k) -> feat col (45+rank) or -1
struct Tbl3 { short col[729]; };
static constexpr Tbl3 make_tbl3() {
    Tbl3 t{};
    for (int x = 0; x < 729; ++x) t.col[x] = -1;
    int r = 0;
    for (int i = 0; i < 9; ++i)
        for (int j = 0; j < 9; ++j)
            for (int k = 0; k < 9; ++k) {
                bool lt1 = (i < j) || (i == j && (j < k || (j == k && k < i)));
                bool lt2 = (i < k) || (i == k && (j < i || (j == i && k < j)));
                if (lt1 && lt2) { t.col[(i*9+j)*9+k] = (short)(45 + r); ++r; }
            }
    return t;
}
static constexpr Tbl3 TBL3 = make_tbl3();

// ============================================================================
// Signature kernel: one lane per (window, slab i).  Lane keeps S3[i][.][.]
// (81 regs), S2 row i (9), S1_i.  128 threads = 2 waves = 14 windows/block.
// amdgpu_waves_per_eu(2) -> VGPR budget 256: the ~130-reg state MUST NOT spill
// (round 1: heuristic capped at 84 VGPR -> 9.2 GB scratch writes, 92 us).
// ============================================================================
__global__ __launch_bounds__(128) __attribute__((amdgpu_waves_per_eu(2)))
void sig_kernel(const float* __restrict__ x, __hip_bfloat16* __restrict__ feats) {
    __shared__ __align__(16) float X[73 * 8];
    __shared__ float S2buf[WPB * 81];
    __shared__ float S1buf[WPB * 9];

    const int blk = blockIdx.x;
    const int b   = blk / SBLK;
    const int s0  = (blk % SBLK) * WPB;
    const int lo  = (s0 - 59 > 0) ? (s0 - 59) : 0;
    const int hi  = (s0 + WPB - 1 < NS - 1) ? (s0 + WPB - 1) : (NS - 1);
    const int nrow = hi - lo + 1;     // <= 73
    const int tid = threadIdx.x;

    {   // stage x[b, lo..hi, 0..7] -> LDS (row-major [pos][ch])
        const float4* src = (const float4*)(x + ((size_t)b * NS + lo) * 8);
        float4* dst = (float4*)X;
        const int n4 = nrow * 2;
        for (int t = tid; t < n4; t += 128) dst[t] = src[t];
    }
    __syncthreads();

    const int lane = tid & 63;
    const int wave = tid >> 6;
    const int wl   = lane / 9;            // 0..7 (7 == idle duplicate lane)
    const int ci   = lane - wl * 9;       // slab index i in 0..8
    const int wl6  = (wl < 6) ? wl : 6;
    const int widx = wave * 7 + wl6;      // 0..13
    const int s    = s0 + widx;
    const bool act = (wl < 7) && (s < NS);

    float S3[9][9];
    float S2r[9];
    float S1i = 0.0f;
#pragma unroll
    for (int a = 0; a < 9; ++a) {
        S2r[a] = 0.0f;
#pragma unroll
        for (int c = 0; c < 9; ++c) S3[a][c] = 0.0f;
    }
    float prev[8];
#pragma unroll
    for (int c = 0; c < 8; ++c) prev[c] = 0.0f;
    float pscal = 0.0f;
    const int ioff = (ci > 0) ? (ci - 1) : 0;
    const int sm59 = s - 59;
    const float DT = 1.0f / 59.0f;

#pragma unroll 1
    for (int j = 0; j < 60; ++j) {
        int g = sm59 + j; g = (g > 0) ? g : 0;          // left-clamped window index
        const float* row = &X[(g - lo) * 8];
        const float4 c0 = *(const float4*)(row);
        const float4 c1 = *(const float4*)(row + 4);
        const float rs  = row[ioff];                    // scalar for this lane's slab
        const float dtj = (j == 0) ? 0.0f : DT;         // time-channel increment
        float v[9];
        v[0] = dtj;
        v[1] = c0.x - prev[0]; v[2] = c0.y - prev[1];
        v[3] = c0.z - prev[2]; v[4] = c0.w - prev[3];
        v[5] = c1.x - prev[4]; v[6] = c1.y - prev[5];
        v[7] = c1.z - prev[6]; v[8] = c1.w - prev[7];
        const float vi = (ci == 0) ? dtj : (rs - pscal);
        // S3 update first (old S1, S2):  S3[j][k] += (S2r[j] + (S1i/2 + vi/6)*v[j]) * v[k]
        const float hh = 0.5f * S1i + vi * (1.0f / 6.0f);
#pragma unroll
        for (int a = 0; a < 9; ++a) {
            const float ra = S2r[a] + hh * v[a];
#pragma unroll
            for (int c = 0; c < 9; ++c) S3[a][c] += ra * v[c];
        }
        // S2 update (old S1):  S2r[j] += (S1i + vi/2) * v[j]
        const float aa = S1i + 0.5f * vi;
#pragma unroll
        for (int a = 0; a < 9; ++a) S2r[a] += aa * v[a];
        S1i += vi;
        prev[0] = c0.x; prev[1] = c0.y; prev[2] = c0.z; prev[3] = c0.w;
        prev[4] = c1.x; prev[5] = c1.y; prev[6] = c1.z; prev[7] = c1.w;
        pscal = rs;
    }

    // cross-slab exchange (once): full S1 and S2 of each window into LDS
    if (wl < 7) {
        S1buf[widx * 9 + ci] = S1i;
#pragma unroll
        for (int a = 0; a < 9; ++a) S2buf[widx * 81 + ci * 9 + a] = S2r[a];
    }
    __syncthreads();

    float s1v[9];
#pragma unroll
    for (int a = 0; a < 9; ++a) s1v[a] = S1buf[widx * 9 + a];
    const float* S2w = &S2buf[widx * 81];

    __hip_bfloat16* frow = feats + (size_t)(b * NS + (act ? s : 0)) * KPAD;
    if (act) {
        // L1 = S1
        frow[ci] = __float2bfloat16(S1i);
        // L2[i,j] = S2[i,j] - 0.5 S1_i S1_j   (i<j), col = 9 + rank
#pragma unroll
        for (int j2 = 0; j2 < 9; ++j2) {
            if (ci < j2) {
                const float val = S2r[j2] - 0.5f * S1i * s1v[j2];
                const int col = 9 + ci * 8 - (ci * (ci - 1)) / 2 + (j2 - ci - 1);
                frow[col] = __float2bfloat16(val);
            }
        }
        if (ci == 0) {  // zero the K padding
            frow[285] = __float2bfloat16(0.0f);
            frow[286] = __float2bfloat16(0.0f);
            frow[287] = __float2bfloat16(0.0f);
        }
    }
    // L3[i,j,k] = S3 - 0.5(S1_i S2[j,k] + S2[i,j] S1_k) + S1_i S1_j S1_k / 3
#pragma unroll
    for (int jk = 0; jk < 81; ++jk) {
        const int j3 = jk / 9, k3 = jk % 9;
        const int col = TBL3.col[ci * 81 + jk];
        if (act && col >= 0) {
            const float s2jk = S2w[jk];
            const float val = S3[j3][k3]
                - 0.5f * (S1i * s2jk + S2r[j3] * s1v[k3])
                + S1i * s1v[j3] * s1v[k3] * (1.0f / 3.0f);
            frow[col] = __float2bfloat16(val);
        }
    }
}

// ============================================================================
// Weight transpose/cast kernels (tiny): w1[285][512]f32 -> w1T[512][288]bf16,
// w2[512][256]f32 -> w2T[256][512]bf16.  [n][k] layout => B-frag ds_read_b128.
// ============================================================================
__global__ void convert_w1(const float* __restrict__ w1, __hip_bfloat16* __restrict__ w1T) {
    const int n = blockIdx.x;          // 0..511
    const int k = threadIdx.x;         // 0..287
    const float v = (k < 285) ? w1[(size_t)k * H2 + n] : 0.0f;
    w1T[(size_t)n * KPAD + k] = __float2bfloat16(v);
}
__global__ void convert_w2(const float* __restrict__ w2, __hip_bfloat16* __restrict__ w2T) {
    const int n = blockIdx.x;          // 0..255
    const int k = threadIdx.x;         // 0..511
    w2T[(size_t)n * H2 + k] = __float2bfloat16(w2[(size_t)k * HID + n]);
}

// ============================================================================
// GEMM1: h = LN(GELU(feats @ w1 + b1)) -> bf16.  Block = 64 rows x 512 cols
// (full N so LN is fusable).  8 waves, wave tile 64x64, 16x16x32 bf16 MFMA.
// Staging via global_load_lds_dwordx4 (async, no VGPR round-trip).
// ============================================================================
__global__ __launch_bounds__(512) __attribute__((amdgpu_waves_per_eu(2)))
void gemm1_kernel(
        const __hip_bfloat16* __restrict__ feats,
        const __hip_bfloat16* __restrict__ w1T,
        const float* __restrict__ b1,
        const float* __restrict__ lng,
        const float* __restrict__ lnb,
        __hip_bfloat16* __restrict__ hbuf) {
    __shared__ __align__(16) __hip_bfloat16 ldsA[64 * 32];
    __shared__ __align__(16) __hip_bfloat16 ldsB[512 * 32];
    __shared__ float lnpart[8][64][2];
    __shared__ float lnstat[64][2];

    const int tid  = threadIdx.x;
    const int wave = tid >> 6;
    const int lane = tid & 63;
    const int quad = lane >> 4;
    const int l16  = lane & 15;
    const int m0   = blockIdx.x * 64;

    f32x4 acc[4][4];
#pragma unroll
    for (int mf = 0; mf < 4; ++mf)
#pragma unroll
        for (int nf = 0; nf < 4; ++nf) acc[mf][nf] = (f32x4){0.f, 0.f, 0.f, 0.f};

    for (int kt = 0; kt < 9; ++kt) {
        const int K0 = kt * 32;
        if (tid < 256) {               // A tile 64x32: waves 0-3, lane order == LDS order
            const int m = tid >> 2, kc = tid & 3;
            gl2lds16(feats + (size_t)(m0 + m) * KPAD + K0 + kc * 8,
                     (char*)ldsA + (tid & ~63) * 16);
        }
#pragma unroll
        for (int q = 0; q < 4; ++q) {  // B tile 512x32 ([n][k])
            const int chunk = q * 512 + tid;
            const int n = chunk >> 2, kc = chunk & 3;
            gl2lds16(w1T + (size_t)n * KPAD + K0 + kc * 8,
                     (char*)ldsB + (chunk & ~63) * 16);
        }
        __syncthreads();
        short8 bfrag[4];
#pragma unroll
        for (int nf = 0; nf < 4; ++nf) {
            const int n = wave * 64 + nf * 16 + l16;
            bfrag[nf] = *(const short8*)(ldsB + n * 32 + quad * 8);
        }
#pragma unroll
        for (int mf = 0; mf < 4; ++mf) {
            const short8 afrag = *(const short8*)(ldsA + (mf * 16 + l16) * 32 + quad * 8);
#pragma unroll
            for (int nf = 0; nf < 4; ++nf)
                acc[mf][nf] = __builtin_amdgcn_mfma_f32_16x16x32_bf16(afrag, bfrag[nf], acc[mf][nf], 0, 0, 0);
        }
        __syncthreads();
    }

    // ---- epilogue: bias + exact GELU IN PLACE (C frag: row = quad*4+reg, col = l16) ----
    float bias[4];
#pragma unroll
    for (int nf = 0; nf < 4; ++nf) bias[nf] = b1[wave * 64 + nf * 16 + l16];
#pragma unroll
    for (int mf = 0; mf < 4; ++mf)
#pragma unroll
        for (int nf = 0; nf < 4; ++nf)
#pragma unroll
            for (int r = 0; r < 4; ++r) {
                const float xv = acc[mf][nf][r] + bias[nf];
                acc[mf][nf][r] = 0.5f * xv * (1.0f + erff(xv * 0.70710678118654752f));
            }
    // LayerNorm: per-row sum/sumsq; reduce over 16 lanes (cols) then 8 waves
    float psum[4][4], psq[4][4];
#pragma unroll
    for (int mf = 0; mf < 4; ++mf)
#pragma unroll
        for (int r = 0; r < 4; ++r) {
            float su = 0.f, sq = 0.f;
#pragma unroll
            for (int nf = 0; nf < 4; ++nf) { const float t = acc[mf][nf][r]; su += t; sq += t * t; }
            psum[mf][r] = su; psq[mf][r] = sq;
        }
#pragma unroll
    for (int d = 1; d < 16; d <<= 1) {
#pragma unroll
        for (int mf = 0; mf < 4; ++mf)
#pragma unroll
            for (int r = 0; r < 4; ++r) {
                psum[mf][r] += __shfl_xor(psum[mf][r], d);
                psq[mf][r]  += __shfl_xor(psq[mf][r], d);
            }
    }
    if (l16 == 0) {
#pragma unroll
        for (int mf = 0; mf < 4; ++mf)
#pragma unroll
            for (int r = 0; r < 4; ++r) {
                const int rrow = mf * 16 + quad * 4 + r;
                lnpart[wave][rrow][0] = psum[mf][r];
                lnpart[wave][rrow][1] = psq[mf][r];
            }
    }
    __syncthreads();
    if (tid < 64) {
        float su = 0.f, sq = 0.f;
#pragma unroll
        for (int w = 0; w < 8; ++w) { su += lnpart[w][tid][0]; sq += lnpart[w][tid][1]; }
        const float mu  = su * (1.0f / 512.0f);
        const float var = sq * (1.0f / 512.0f) - mu * mu;   // population var (ddof=0)
        lnstat[tid][0] = mu;
        lnstat[tid][1] = rsqrtf(var + 1e-5f);
    }
    __syncthreads();
    float gv[4], bv[4];
#pragma unroll
    for (int nf = 0; nf < 4; ++nf) {
        const int col = wave * 64 + nf * 16 + l16;
        gv[nf] = lng[col]; bv[nf] = lnb[col];
    }
#pragma unroll
    for (int mf = 0; mf < 4; ++mf)
#pragma unroll
        for (int r = 0; r < 4; ++r) {
            const int rrow = mf * 16 + quad * 4 + r;
            const float mu = lnstat[rrow][0];
            const float rstd = lnstat[rrow][1];
#pragma unroll
            for (int nf = 0; nf < 4; ++nf) {
                const float hn = (acc[mf][nf][r] - mu) * rstd * gv[nf] + bv[nf];
                hbuf[(size_t)(m0 + rrow) * H2 + wave * 64 + nf * 16 + l16] = __float2bfloat16(hn);
            }
        }
}

// ============================================================================
// GEMM2: out = h @ w2 + b2 (fp32 out). Block = 64 rows x 256 cols, 8 waves,
// wave tile 64x32, K=512 in 16 steps of 32.
// ============================================================================
__global__ __launch_bounds__(512) __attribute__((amdgpu_waves_per_eu(2)))
void gemm2_kernel(
        const __hip_bfloat16* __restrict__ hbuf,
        const __hip_bfloat16* __restrict__ w2T,
        const float* __restrict__ b2,
        float* __restrict__ out) {
    __shared__ __align__(16) __hip_bfloat16 ldsA[64 * 32];
    __shared__ __align__(16) __hip_bfloat16 ldsB[256 * 32];
    const int tid  = threadIdx.x;
    const int wave = tid >> 6;
    const int lane = tid & 63;
    const int quad = lane >> 4;
    const int l16  = lane & 15;
    const int m0   = blockIdx.x * 64;

    f32x4 acc[4][2];
#pragma unroll
    for (int mf = 0; mf < 4; ++mf)
#pragma unroll
        for (int nf = 0; nf < 2; ++nf) acc[mf][nf] = (f32x4){0.f, 0.f, 0.f, 0.f};

    for (int kt = 0; kt < 16; ++kt) {
        const int K0 = kt * 32;
        if (tid < 256) {
            const int m = tid >> 2, kc = tid & 3;
            gl2lds16(hbuf + (size_t)(m0 + m) * H2 + K0 + kc * 8,
                     (char*)ldsA + (tid & ~63) * 16);
        }
#pragma unroll
        for (int q = 0; q < 2; ++q) {
            const int chunk = q * 512 + tid;
            const int n = chunk >> 2, kc = chunk & 3;
            gl2lds16(w2T + (size_t)n * H2 + K0 + kc * 8,
                     (char*)ldsB + (chunk & ~63) * 16);
        }
        __syncthreads();
        short8 bfrag[2];
#pragma unroll
        for (int nf = 0; nf < 2; ++nf) {
            const int n = wave * 32 + nf * 16 + l16;
            bfrag[nf] = *(const short8*)(ldsB + n * 32 + quad * 8);
        }
#pragma unroll
        for (int mf = 0; mf < 4; ++mf) {
            const short8 afrag = *(const short8*)(ldsA + (mf * 16 + l16) * 32 + quad * 8);
#pragma unroll
            for (int nf = 0; nf < 2; ++nf)
                acc[mf][nf] = __builtin_amdgcn_mfma_f32_16x16x32_bf16(afrag, bfrag[nf], acc[mf][nf], 0, 0, 0);
        }
        __syncthreads();
    }
    float bb[2];
#pragma unroll
    for (int nf = 0; nf < 2; ++nf) bb[nf] = b2[wave * 32 + nf * 16 + l16];
#pragma unroll
    for (int mf = 0; mf < 4; ++mf)
#pragma unroll
        for (int r = 0; r < 4; ++r) {
            const int rrow = mf * 16 + quad * 4 + r;
#pragma unroll
            for (int nf = 0; nf < 2; ++nf)
                out[(size_t)(m0 + rrow) * HID + wave * 32 + nf * 16 + l16] = acc[mf][nf][r] + bb[nf];
        }
}

// ============================================================================
extern "C" void kernel_launch(void* const* d_in, const int* in_sizes, int n_in,
                              void* d_out, int out_size, void* d_ws, size_t ws_size,
                              hipStream_t stream) {
    const float* x   = (const float*)d_in[0];
    const float* w1  = (const float*)d_in[1];
    const float* b1  = (const float*)d_in[2];
    const float* lng = (const float*)d_in[3];
    const float* lnb = (const float*)d_in[4];
    const float* w2  = (const float*)d_in[5];
    const float* b2  = (const float*)d_in[6];
    float* out = (float*)d_out;

    char* ws = (char*)d_ws;
    __hip_bfloat16* feats = (__hip_bfloat16*)(ws);                       // 16384*288*2 = 9437184
    __hip_bfloat16* hbuf  = (__hip_bfloat16*)(ws + 9437184);             // 16384*512*2 = 16777216
    __hip_bfloat16* w1T   = (__hip_bfloat16*)(ws + 9437184 + 16777216);  // 512*288*2  = 294912
    __hip_bfloat16* w2T   = (__hip_bfloat16*)(ws + 9437184 + 16777216 + 294912); // 256*512*2

    convert_w1<<<dim3(512), dim3(288), 0, stream>>>(w1, w1T);
    convert_w2<<<dim3(256), dim3(512), 0, stream>>>(w2, w2T);
    sig_kernel<<<dim3(8 * SBLK), dim3(128), 0, stream>>>(x, feats);
    gemm1_kernel<<<dim3(16384 / 64), dim3(512), 0, stream>>>(feats, w1T, b1, lng, lnb, hbuf);
    gemm2_kernel<<<dim3(16384 / 64), dim3(512), 0, stream>>>(hbuf, w2T, b2, out);
}